// Round 12
// baseline (156.149 us; speedup 1.0000x reference)
//
#include <hip/hip_runtime.h>
#include <hip/hip_bf16.h>

#define CDIM 4096
#define DDIM 1024
#define BDIM 16384
#define EDIAG 2.7182818284590452f

using frag_ab = __attribute__((ext_vector_type(8))) short;   // 8 bf16 (4 VGPRs)
using frag_cd = __attribute__((ext_vector_type(4))) float;   // 4 fp32
using f32x4   = __attribute__((ext_vector_type(4))) float;   // native vec for nt-load

typedef __attribute__((address_space(1))) const void gvoid;
typedef __attribute__((address_space(3))) void lvoid;

__device__ __forceinline__ float block_sum(float v, float* red) {
  int t = threadIdx.x;
  #pragma unroll
  for (int off = 32; off; off >>= 1) v += __shfl_xor(v, off);
  __syncthreads();
  if ((t & 63) == 0) red[t >> 6] = v;
  __syncthreads();
  return (red[0] + red[1]) + (red[2] + red[3]);
}

__device__ __forceinline__ unsigned short f2bfbits(float f) {
  __hip_bfloat16 b = __float2bfloat16(f);
  return *(unsigned short*)&b;
}

// fp8 e4m3 (OCP on gfx950) pack/unpack via HW cvt
__device__ __forceinline__ unsigned char f2fp8(float x) {
  int p = __builtin_amdgcn_cvt_pk_fp8_f32(x, x, 0, false);
  return (unsigned char)(p & 0xff);
}

// ---- Kernel A: wn = bf16( weight_row / max(||row||, 1e-8) ); zero Sf ----
__global__ __launch_bounds__(256) void k_norm(const float* __restrict__ w,
                                              __hip_bfloat16* __restrict__ wnb,
                                              float* __restrict__ Sf) {
  __shared__ float red[4];
  __shared__ float s_inv;
  int row = blockIdx.x, t = threadIdx.x;
  const float4* wr = (const float4*)(w + (size_t)row * DDIM);
  float4 x = wr[t];
  float ss = (x.x * x.x + x.y * x.y) + (x.z * x.z + x.w * x.w);
  ss = block_sum(ss, red);
  if (t == 0) {
    s_inv = 1.0f / fmaxf(sqrtf(ss), 1e-8f);
    Sf[row] = 0.0f;
  }
  __syncthreads();
  float inv = s_inv;
  ushort4 o;
  o.x = f2bfbits(x.x * inv);
  o.y = f2bfbits(x.y * inv);
  o.z = f2bfbits(x.z * inv);
  o.w = f2bfbits(x.w * inv);
  *(ushort4*)(wnb + (size_t)row * DDIM + t * 4) = o;
}

// ---- Kernel B: e8 = fp8(exp(wn @ wn^T)), upper-triangle blocks only (R9 cfg) ----
__global__ __launch_bounds__(512) void k_simexp(const __hip_bfloat16* __restrict__ wb,
                                                unsigned char* __restrict__ e8,
                                                float* __restrict__ Sf) {
  __shared__ char smem[65536];                 // 2 bufs x (A[128][64]|B[128][64]) bf16
  int tid = threadIdx.x;
  int lane = tid & 63, wid = tid >> 6;
  int l15 = lane & 15, lk = (lane >> 4) * 8;
  int wm = wid >> 2, wn4 = wid & 3;            // 2x4 waves, each 64x32 output

  // upper-triangle decode: pairs (brow<=bcol)
  int bi = blockIdx.x;
  int r = (int)((65.0f - sqrtf(4225.0f - 8.0f * (float)bi)) * 0.5f);
  if (r < 0) r = 0; if (r > 31) r = 31;
  while (r * (65 - r) / 2 > bi) --r;
  while ((r + 1) * (64 - r) / 2 <= bi) ++r;
  int brow = r;
  int bcol = r + (bi - r * (65 - r) / 2);
  bool diag = (brow == bcol);

  int srow = tid >> 3;
  int swzel = ((tid & 7) ^ (srow & 7)) * 8;
  const __hip_bfloat16* gA0 = wb + (size_t)(brow * 128 + srow) * DDIM + swzel;
  const __hip_bfloat16* gA1 = gA0 + (size_t)64 * DDIM;
  const __hip_bfloat16* gB0 = wb + (size_t)(bcol * 128 + srow) * DDIM + swzel;
  const __hip_bfloat16* gB1 = gB0 + (size_t)64 * DDIM;
  int ldst = tid * 16;

#define STAGE(bufbase, k0)                                                                  \
  do {                                                                                      \
    __builtin_amdgcn_global_load_lds((gvoid*)(gA0 + (k0)), (lvoid*)(smem + (bufbase) + ldst),         16, 0, 0); \
    __builtin_amdgcn_global_load_lds((gvoid*)(gA1 + (k0)), (lvoid*)(smem + (bufbase) + 8192 + ldst),  16, 0, 0); \
    __builtin_amdgcn_global_load_lds((gvoid*)(gB0 + (k0)), (lvoid*)(smem + (bufbase) + 16384 + ldst), 16, 0, 0); \
    __builtin_amdgcn_global_load_lds((gvoid*)(gB1 + (k0)), (lvoid*)(smem + (bufbase) + 24576 + ldst), 16, 0, 0); \
  } while (0)

  int xorb = (l15 & 7) << 4;
  int aoff = (wm * 64 + l15) * 128;
  int boff = 16384 + (wn4 * 32 + l15) * 128;

  frag_cd acc[4][2] = {};

  STAGE(0, 0);
  __syncthreads();
  int cur = 0;
  for (int t = 0; t < 16; t++) {
    if (t < 15) STAGE((cur ^ 1) * 32768, (t + 1) * 64);
    const char* base = smem + cur * 32768;
    const char* pa0 = base + aoff;
    const char* pb0 = base + boff;
    #pragma unroll
    for (int ks = 0; ks < 2; ks++) {
      int off = ((ks * 32 + lk) * 2) ^ xorb;
      frag_ab a[4], b[2];
      #pragma unroll
      for (int m = 0; m < 4; m++) a[m] = *(const frag_ab*)(const void*)(pa0 + m * 2048 + off);
      #pragma unroll
      for (int n = 0; n < 2; n++) b[n] = *(const frag_ab*)(const void*)(pb0 + n * 2048 + off);
      #pragma unroll
      for (int m = 0; m < 4; m++)
        #pragma unroll
        for (int n = 0; n < 2; n++)
          acc[m][n] = __builtin_amdgcn_mfma_f32_16x16x32_bf16(a[m], b[n], acc[m][n], 0, 0, 0);
    }
    __syncthreads();
    cur ^= 1;
  }
#undef STAGE

  #pragma unroll
  for (int m = 0; m < 4; m++)
    #pragma unroll
    for (int n = 0; n < 2; n++)
      #pragma unroll
      for (int j = 0; j < 4; j++)
        acc[m][n][j] = __expf(acc[m][n][j]);

  int rg = (lane >> 4) * 4;
  int r0g = brow * 128 + wm * 64;
  int c0g = bcol * 128 + wn4 * 32 + l15;

  #pragma unroll
  for (int m = 0; m < 4; m++)
    #pragma unroll
    for (int j = 0; j < 4; j++) {
      int rglob = r0g + m * 16 + rg + j;
      float rsum = 0.f;
      #pragma unroll
      for (int n = 0; n < 2; n++) {
        float ex = acc[m][n][j];
        e8[(size_t)rglob * CDIM + c0g + n * 16] = f2fp8(ex);
        rsum += ex;
      }
      rsum += __shfl_xor(rsum, 1);
      rsum += __shfl_xor(rsum, 2);
      rsum += __shfl_xor(rsum, 4);
      rsum += __shfl_xor(rsum, 8);
      if (l15 == 0) atomicAdd(&Sf[rglob], rsum);
    }

  if (!diag) {
    #pragma unroll
    for (int n = 0; n < 2; n++) {
      int cloc = wn4 * 32 + n * 16 + l15;
      int xc = (cloc & 7) << 4;
      #pragma unroll
      for (int m = 0; m < 4; m++)
        #pragma unroll
        for (int j = 0; j < 4; j++) {
          int rloc = wm * 64 + m * 16 + rg + j;
          smem[cloc * 128 + (rloc ^ xc)] = (char)f2fp8(acc[m][n][j]);
        }
      float cs = 0.f;
      #pragma unroll
      for (int mm = 0; mm < 4; mm++)
        #pragma unroll
        for (int j = 0; j < 4; j++) cs += acc[mm][n][j];
      cs += __shfl_xor(cs, 16);
      cs += __shfl_xor(cs, 32);
      if (lane < 16) atomicAdd(&Sf[bcol * 128 + wn4 * 32 + n * 16 + l15], cs);
    }
    __syncthreads();
    #pragma unroll
    for (int it = 0; it < 4; it++) {
      int ct = it * 32 + (tid >> 4);
      int rch = (tid & 15) * 8;
      uint2 v = *(const uint2*)(const void*)(smem + ct * 128 + (rch ^ ((ct & 7) << 4)));
      *(uint2*)(void*)(e8 + (size_t)(bcol * 128 + ct) * CDIM + brow * 128 + rch) = v;
    }
  }
}

// ---- MEASUREMENT VARIANT: k_loss WITHOUT the e8 gather (writes scratch part2) ----
// Identical pred stream + exp + reductions + Sf read; no e8 access. Dropped next round.
__global__ __launch_bounds__(256) void k_loss_ng(const float* __restrict__ pred,
                                                 const int* __restrict__ tgt,
                                                 const float* __restrict__ Sf,
                                                 float* __restrict__ part2) {
  __shared__ float reds[4];
  int i = blockIdx.x, t = threadIdx.x;
  int tg = tgt[i];
  const f32x4* pr = (const f32x4*)(pred + (size_t)i * CDIM);

  float se = 0.f;
  #pragma unroll
  for (int j = 0; j < 4; j++) {
    f32x4 v = __builtin_nontemporal_load(pr + t + j * 256);
    se += (__expf(v[0]) + __expf(v[1])) + (__expf(v[2]) + __expf(v[3]));
  }
  #pragma unroll
  for (int off = 32; off; off >>= 1) se += __shfl_xor(se, off);
  if ((t & 63) == 0) reds[t >> 6] = se;
  __syncthreads();
  if (t == 0) {
    se = (reds[0] + reds[1]) + (reds[2] + reds[3]);
    float lse = __logf(se);
    float pt = pred[(size_t)i * CDIM + tg];
    float ce = lse - pt;
    float S = Sf[tg];
    float t2 = (S * lse - EDIAG * ce) / (S - EDIAG);   // no dot term
    part2[i] = 0.9f * ce + 0.1f * t2;
  }
}

// ---- Kernel C: per-sample loss (R9 config: 1 sample/block, no max, nt loads) ----
__global__ __launch_bounds__(256) void k_loss(const float* __restrict__ pred,
                                              const int* __restrict__ tgt,
                                              const unsigned char* __restrict__ e8,
                                              const float* __restrict__ Sf,
                                              float* __restrict__ part) {
  __shared__ float reds[4], redd[4];
  int i = blockIdx.x, t = threadIdx.x;
  int tg = tgt[i];
  const f32x4* pr = (const f32x4*)(pred + (size_t)i * CDIM);
  const unsigned int* er = (const unsigned int*)(e8 + (size_t)tg * CDIM);

  float se = 0.f, dot = 0.f;
  #pragma unroll
  for (int j = 0; j < 4; j++) {
    f32x4 v = __builtin_nontemporal_load(pr + t + j * 256);
    unsigned int ev = er[t + j * 256];
    se += (__expf(v[0]) + __expf(v[1])) + (__expf(v[2]) + __expf(v[3]));
    dot += __builtin_amdgcn_cvt_f32_fp8(ev, 0) * v[0] +
           __builtin_amdgcn_cvt_f32_fp8(ev, 1) * v[1] +
           __builtin_amdgcn_cvt_f32_fp8(ev, 2) * v[2] +
           __builtin_amdgcn_cvt_f32_fp8(ev, 3) * v[3];
  }
  #pragma unroll
  for (int off = 32; off; off >>= 1) {
    se += __shfl_xor(se, off);
    dot += __shfl_xor(dot, off);
  }
  if ((t & 63) == 0) { reds[t >> 6] = se; redd[t >> 6] = dot; }
  __syncthreads();
  if (t == 0) {
    se = (reds[0] + reds[1]) + (reds[2] + reds[3]);
    dot = (redd[0] + redd[1]) + (redd[2] + redd[3]);
    float lse = __logf(se);
    float pt = pred[(size_t)i * CDIM + tg];
    float ce = lse - pt;
    float S = Sf[tg];
    float t2 = (S * lse - dot - EDIAG * ce) / (S - EDIAG);
    part[i] = 0.9f * ce + 0.1f * t2;
  }
}

// ---- Kernel D: deterministic final reduce ----
__global__ __launch_bounds__(256) void k_final(const float* __restrict__ part,
                                               float* __restrict__ out) {
  __shared__ float red[4];
  int t = threadIdx.x;
  float s = 0.f;
  for (int i = t; i < BDIM; i += 256) s += part[i];
  s = block_sum(s, red);
  if (t == 0) out[0] = s * (1.0f / BDIM);
}

extern "C" void kernel_launch(void* const* d_in, const int* in_sizes, int n_in,
                              void* d_out, int out_size, void* d_ws, size_t ws_size,
                              hipStream_t stream) {
  const float* pred = (const float*)d_in[0];
  const float* weight = (const float*)d_in[1];
  const int* target = (const int*)d_in[2];
  float* out = (float*)d_out;
  char* ws = (char*)d_ws;

  __hip_bfloat16* wnb = (__hip_bfloat16*)ws;                          // 8 MB
  unsigned char* e8 = (unsigned char*)(ws + (size_t)(8u << 20));      // 16 MB
  float* Sf    = (float*)(ws + (size_t)(24u << 20));                  // 16 KB
  float* part  = (float*)(ws + (size_t)(24u << 20) + 16384);          // 64 KB
  float* part2 = (float*)(ws + (size_t)(24u << 20) + 16384 + 65536);  // 64 KB (scratch)

  k_norm<<<dim3(CDIM), dim3(256), 0, stream>>>(weight, wnb, Sf);
  k_simexp<<<dim3(528), dim3(512), 0, stream>>>(wnb, e8, Sf);
  // MEASUREMENT: pred-stream-only k_loss (no gather). T_total - 117.5 = its cost.
  k_loss_ng<<<dim3(BDIM), dim3(256), 0, stream>>>(pred, target, Sf, part2);
  k_loss<<<dim3(BDIM), dim3(256), 0, stream>>>(pred, target, e8, Sf, part);
  k_final<<<dim3(1), dim3(256), 0, stream>>>(part, out);
}

// Round 13
// 118.857 us; speedup vs baseline: 1.3138x; 1.3138x over previous
//
#include <hip/hip_runtime.h>
#include <hip/hip_bf16.h>

#define CDIM 4096
#define DDIM 1024
#define BDIM 16384
#define EDIAG 2.7182818284590452f
#define QBASE 0.36787944f          // e^-1
#define QSCALE 0.15669957f         // (e - e^-1)/15
#define QINV 6.3816357f            // 1/QSCALE

using frag_ab = __attribute__((ext_vector_type(8))) short;   // 8 bf16 (4 VGPRs)
using frag_cd = __attribute__((ext_vector_type(4))) float;   // 4 fp32
using f32x4   = __attribute__((ext_vector_type(4))) float;   // native vec for nt-load

typedef __attribute__((address_space(1))) const void gvoid;
typedef __attribute__((address_space(3))) void lvoid;

__device__ __forceinline__ float block_sum(float v, float* red) {
  int t = threadIdx.x;
  #pragma unroll
  for (int off = 32; off; off >>= 1) v += __shfl_xor(v, off);
  __syncthreads();
  if ((t & 63) == 0) red[t >> 6] = v;
  __syncthreads();
  return (red[0] + red[1]) + (red[2] + red[3]);
}

__device__ __forceinline__ unsigned short f2bfbits(float f) {
  __hip_bfloat16 b = __float2bfloat16(f);
  return *(unsigned short*)&b;
}

// 4-bit linear quant of e-values (e in [e^-1, e])
__device__ __forceinline__ int q4(float ex) {
  int q = __float2int_rn((ex - QBASE) * QINV);
  return min(15, max(0, q));
}

// ---- Kernel A: wn = bf16( weight_row / max(||row||, 1e-8) ); zero Sf ----
__global__ __launch_bounds__(256) void k_norm(const float* __restrict__ w,
                                              __hip_bfloat16* __restrict__ wnb,
                                              float* __restrict__ Sf) {
  __shared__ float red[4];
  __shared__ float s_inv;
  int row = blockIdx.x, t = threadIdx.x;
  const float4* wr = (const float4*)(w + (size_t)row * DDIM);
  float4 x = wr[t];
  float ss = (x.x * x.x + x.y * x.y) + (x.z * x.z + x.w * x.w);
  ss = block_sum(ss, red);
  if (t == 0) {
    s_inv = 1.0f / fmaxf(sqrtf(ss), 1e-8f);
    Sf[row] = 0.0f;
  }
  __syncthreads();
  float inv = s_inv;
  ushort4 o;
  o.x = f2bfbits(x.x * inv);
  o.y = f2bfbits(x.y * inv);
  o.z = f2bfbits(x.z * inv);
  o.w = f2bfbits(x.w * inv);
  *(ushort4*)(wnb + (size_t)row * DDIM + t * 4) = o;
}

// ---- Kernel B: e4 = u4(exp(wn @ wn^T)), upper-triangle blocks only ----
// 128x128 tile, BK=64, 8 waves (2Mx4N), double-buffered swizzled LDS.
// Normal tile: column-pair nibble pack via shfl_xor(q,1), even lanes store bytes.
// Mirror tile: row-pair (j) nibble pack inside thread -> ushort stores (no LDS round).
// f32 row-sum + mirror col-sum atomics into Sf.
__global__ __launch_bounds__(512) void k_simexp(const __hip_bfloat16* __restrict__ wb,
                                                unsigned char* __restrict__ e4,
                                                float* __restrict__ Sf) {
  __shared__ char smem[65536];                 // 2 bufs x (A[128][64]|B[128][64]) bf16
  int tid = threadIdx.x;
  int lane = tid & 63, wid = tid >> 6;
  int l15 = lane & 15, lk = (lane >> 4) * 8;
  int wm = wid >> 2, wn4 = wid & 3;            // 2x4 waves, each 64x32 output

  // upper-triangle decode: pairs (brow<=bcol)
  int bi = blockIdx.x;
  int r = (int)((65.0f - sqrtf(4225.0f - 8.0f * (float)bi)) * 0.5f);
  if (r < 0) r = 0; if (r > 31) r = 31;
  while (r * (65 - r) / 2 > bi) --r;
  while ((r + 1) * (64 - r) / 2 <= bi) ++r;
  int brow = r;
  int bcol = r + (bi - r * (65 - r) / 2);
  bool diag = (brow == bcol);

  int srow = tid >> 3;
  int swzel = ((tid & 7) ^ (srow & 7)) * 8;
  const __hip_bfloat16* gA0 = wb + (size_t)(brow * 128 + srow) * DDIM + swzel;
  const __hip_bfloat16* gA1 = gA0 + (size_t)64 * DDIM;
  const __hip_bfloat16* gB0 = wb + (size_t)(bcol * 128 + srow) * DDIM + swzel;
  const __hip_bfloat16* gB1 = gB0 + (size_t)64 * DDIM;
  int ldst = tid * 16;

#define STAGE(bufbase, k0)                                                                  \
  do {                                                                                      \
    __builtin_amdgcn_global_load_lds((gvoid*)(gA0 + (k0)), (lvoid*)(smem + (bufbase) + ldst),         16, 0, 0); \
    __builtin_amdgcn_global_load_lds((gvoid*)(gA1 + (k0)), (lvoid*)(smem + (bufbase) + 8192 + ldst),  16, 0, 0); \
    __builtin_amdgcn_global_load_lds((gvoid*)(gB0 + (k0)), (lvoid*)(smem + (bufbase) + 16384 + ldst), 16, 0, 0); \
    __builtin_amdgcn_global_load_lds((gvoid*)(gB1 + (k0)), (lvoid*)(smem + (bufbase) + 24576 + ldst), 16, 0, 0); \
  } while (0)

  int xorb = (l15 & 7) << 4;
  int aoff = (wm * 64 + l15) * 128;
  int boff = 16384 + (wn4 * 32 + l15) * 128;

  frag_cd acc[4][2] = {};

  STAGE(0, 0);
  __syncthreads();
  int cur = 0;
  for (int t = 0; t < 16; t++) {
    if (t < 15) STAGE((cur ^ 1) * 32768, (t + 1) * 64);
    const char* base = smem + cur * 32768;
    const char* pa0 = base + aoff;
    const char* pb0 = base + boff;
    #pragma unroll
    for (int ks = 0; ks < 2; ks++) {
      int off = ((ks * 32 + lk) * 2) ^ xorb;
      frag_ab a[4], b[2];
      #pragma unroll
      for (int m = 0; m < 4; m++) a[m] = *(const frag_ab*)(const void*)(pa0 + m * 2048 + off);
      #pragma unroll
      for (int n = 0; n < 2; n++) b[n] = *(const frag_ab*)(const void*)(pb0 + n * 2048 + off);
      #pragma unroll
      for (int m = 0; m < 4; m++)
        #pragma unroll
        for (int n = 0; n < 2; n++)
          acc[m][n] = __builtin_amdgcn_mfma_f32_16x16x32_bf16(a[m], b[n], acc[m][n], 0, 0, 0);
    }
    __syncthreads();
    cur ^= 1;
  }
#undef STAGE

  // exp in place
  #pragma unroll
  for (int m = 0; m < 4; m++)
    #pragma unroll
    for (int n = 0; n < 2; n++)
      #pragma unroll
      for (int j = 0; j < 4; j++)
        acc[m][n][j] = __expf(acc[m][n][j]);

  // C/D layout: col = lane&15, row = (lane>>4)*4 + reg
  int rg = (lane >> 4) * 4;
  int r0g = brow * 128 + wm * 64;
  int c0g = bcol * 128 + wn4 * 32 + l15;

  // normal tile (nibble-packed via lane pairing) + f32 row sums
  #pragma unroll
  for (int m = 0; m < 4; m++)
    #pragma unroll
    for (int j = 0; j < 4; j++) {
      int rglob = r0g + m * 16 + rg + j;
      float rsum = 0.f;
      #pragma unroll
      for (int n = 0; n < 2; n++) {
        float ex = acc[m][n][j];
        rsum += ex;
        int q = q4(ex);
        int qr = __shfl_xor(q, 1);             // partner column's nibble
        if (!(l15 & 1))
          e4[(size_t)rglob * 2048 + (unsigned)((c0g + n * 16) >> 1)] =
              (unsigned char)(q | (qr << 4));
      }
      rsum += __shfl_xor(rsum, 1);
      rsum += __shfl_xor(rsum, 2);
      rsum += __shfl_xor(rsum, 4);
      rsum += __shfl_xor(rsum, 8);
      if (l15 == 0) atomicAdd(&Sf[rglob], rsum);
    }

  if (!diag) {
    // mirror tile: rows of the mirror are our columns; j-pairs pack in-thread.
    #pragma unroll
    for (int n = 0; n < 2; n++) {
      int cg = c0g + n * 16;                   // global col = mirror row
      #pragma unroll
      for (int m = 0; m < 4; m++) {
        int b0 = q4(acc[m][n][0]) | (q4(acc[m][n][1]) << 4);
        int b1 = q4(acc[m][n][2]) | (q4(acc[m][n][3]) << 4);
        *(unsigned short*)(e4 + (size_t)cg * 2048 + ((unsigned)(r0g + m * 16 + rg) >> 1)) =
            (unsigned short)(b0 | (b1 << 8));
      }
      // col sums -> mirror rows' Sf
      float cs = 0.f;
      #pragma unroll
      for (int mm = 0; mm < 4; mm++)
        #pragma unroll
        for (int j = 0; j < 4; j++) cs += acc[mm][n][j];
      cs += __shfl_xor(cs, 16);
      cs += __shfl_xor(cs, 32);
      if (lane < 16) atomicAdd(&Sf[cg], cs);
    }
  }
}

// ---- Kernel C: per-sample loss (1 sample/block, no max, nt pred loads, u4 gather) ----
__global__ __launch_bounds__(256) void k_loss(const float* __restrict__ pred,
                                              const int* __restrict__ tgt,
                                              const unsigned char* __restrict__ e4,
                                              const float* __restrict__ Sf,
                                              float* __restrict__ part) {
  __shared__ float reds[4], redq[4], redp[4];
  int i = blockIdx.x, t = threadIdx.x;
  int tg = tgt[i];
  const f32x4* pr = (const f32x4*)(pred + (size_t)i * CDIM);
  const unsigned short* er = (const unsigned short*)(e4 + (size_t)tg * 2048);

  float se = 0.f, sp = 0.f, qd = 0.f;
  #pragma unroll
  for (int j = 0; j < 4; j++) {
    f32x4 v = __builtin_nontemporal_load(pr + t + j * 256);
    unsigned int u = er[t + j * 256];          // 4 nibbles = 4 columns
    se += (__expf(v[0]) + __expf(v[1])) + (__expf(v[2]) + __expf(v[3]));
    sp += (v[0] + v[1]) + (v[2] + v[3]);
    qd += (float)(u & 15u) * v[0] +
          (float)((u >> 4) & 15u) * v[1] +
          (float)((u >> 8) & 15u) * v[2] +
          (float)(u >> 12) * v[3];
  }
  #pragma unroll
  for (int off = 32; off; off >>= 1) {
    se += __shfl_xor(se, off);
    sp += __shfl_xor(sp, off);
    qd += __shfl_xor(qd, off);
  }
  if ((t & 63) == 0) { reds[t >> 6] = se; redq[t >> 6] = qd; redp[t >> 6] = sp; }
  __syncthreads();
  if (t == 0) {
    se = (reds[0] + reds[1]) + (reds[2] + reds[3]);
    qd = (redq[0] + redq[1]) + (redq[2] + redq[3]);
    sp = (redp[0] + redp[1]) + (redp[2] + redp[3]);
    float dot = QSCALE * qd + QBASE * sp;
    float lse = __logf(se);
    float pt = pred[(size_t)i * CDIM + tg];
    float ce = lse - pt;
    float S = Sf[tg];
    float t2 = (S * lse - dot - EDIAG * ce) / (S - EDIAG);
    part[i] = 0.9f * ce + 0.1f * t2;
  }
}

// ---- Kernel D: deterministic final reduce ----
__global__ __launch_bounds__(256) void k_final(const float* __restrict__ part,
                                               float* __restrict__ out) {
  __shared__ float red[4];
  int t = threadIdx.x;
  float s = 0.f;
  for (int i = t; i < BDIM; i += 256) s += part[i];
  s = block_sum(s, red);
  if (t == 0) out[0] = s * (1.0f / BDIM);
}

extern "C" void kernel_launch(void* const* d_in, const int* in_sizes, int n_in,
                              void* d_out, int out_size, void* d_ws, size_t ws_size,
                              hipStream_t stream) {
  const float* pred = (const float*)d_in[0];
  const float* weight = (const float*)d_in[1];
  const int* target = (const int*)d_in[2];
  float* out = (float*)d_out;
  char* ws = (char*)d_ws;

  __hip_bfloat16* wnb = (__hip_bfloat16*)ws;                          // 8 MB
  unsigned char* e4 = (unsigned char*)(ws + (size_t)(8u << 20));      // 8 MB (u4-packed)
  float* Sf   = (float*)(ws + (size_t)(16u << 20));                   // 16 KB
  float* part = (float*)(ws + (size_t)(16u << 20) + 16384);           // 64 KB

  k_norm<<<dim3(CDIM), dim3(256), 0, stream>>>(weight, wnb, Sf);
  k_simexp<<<dim3(528), dim3(512), 0, stream>>>(wnb, e4, Sf);
  k_loss<<<dim3(BDIM), dim3(256), 0, stream>>>(pred, target, e4, Sf, part);
  k_final<<<dim3(1), dim3(256), 0, stream>>>(part, out);
}

// Round 14
// 116.247 us; speedup vs baseline: 1.3432x; 1.0224x over previous
//
#include <hip/hip_runtime.h>
#include <hip/hip_bf16.h>

#define CDIM 4096
#define DDIM 1024
#define BDIM 16384
#define EDIAG 2.7182818284590452f
#define QBASE 0.36787944f          // e^-1
#define QSCALE 0.15669957f         // (e - e^-1)/15
#define QINV 6.3816357f            // 1/QSCALE

using frag_ab = __attribute__((ext_vector_type(8))) short;   // 8 bf16 (4 VGPRs)
using frag_cd = __attribute__((ext_vector_type(4))) float;   // 4 fp32
using f32x4   = __attribute__((ext_vector_type(4))) float;   // native vec for nt-load

typedef __attribute__((address_space(1))) const void gvoid;
typedef __attribute__((address_space(3))) void lvoid;

__device__ __forceinline__ float block_sum(float v, float* red) {
  int t = threadIdx.x;
  #pragma unroll
  for (int off = 32; off; off >>= 1) v += __shfl_xor(v, off);
  __syncthreads();
  if ((t & 63) == 0) red[t >> 6] = v;
  __syncthreads();
  return (red[0] + red[1]) + (red[2] + red[3]);
}

__device__ __forceinline__ unsigned short f2bfbits(float f) {
  __hip_bfloat16 b = __float2bfloat16(f);
  return *(unsigned short*)&b;
}

// 4-bit linear quant of e-values (e in [e^-1, e])
__device__ __forceinline__ int q4(float ex) {
  int q = __float2int_rn((ex - QBASE) * QINV);
  return min(15, max(0, q));
}

// ---- Kernel A: wn = bf16( weight_row / max(||row||, 1e-8) ); zero Sf ----
__global__ __launch_bounds__(256) void k_norm(const float* __restrict__ w,
                                              __hip_bfloat16* __restrict__ wnb,
                                              float* __restrict__ Sf) {
  __shared__ float red[4];
  __shared__ float s_inv;
  int row = blockIdx.x, t = threadIdx.x;
  const float4* wr = (const float4*)(w + (size_t)row * DDIM);
  float4 x = wr[t];
  float ss = (x.x * x.x + x.y * x.y) + (x.z * x.z + x.w * x.w);
  ss = block_sum(ss, red);
  if (t == 0) {
    s_inv = 1.0f / fmaxf(sqrtf(ss), 1e-8f);
    Sf[row] = 0.0f;
  }
  __syncthreads();
  float inv = s_inv;
  ushort4 o;
  o.x = f2bfbits(x.x * inv);
  o.y = f2bfbits(x.y * inv);
  o.z = f2bfbits(x.z * inv);
  o.w = f2bfbits(x.w * inv);
  *(ushort4*)(wnb + (size_t)row * DDIM + t * 4) = o;
}

// ---- Kernel B: e4 = u4(exp(wn @ wn^T)), upper-triangle blocks only ----
// 128x128 tile, BK=64, 8 waves (2Mx4N), double-buffered swizzled LDS.
// T4 counted-vmcnt K-loop: prefetch loads stay in flight across raw barriers;
// wait vmcnt(4) (allow newest STAGE's 4 loads) instead of full drain.
__global__ __launch_bounds__(512) void k_simexp(const __hip_bfloat16* __restrict__ wb,
                                                unsigned char* __restrict__ e4,
                                                float* __restrict__ Sf) {
  __shared__ char smem[65536];                 // 2 bufs x (A[128][64]|B[128][64]) bf16
  int tid = threadIdx.x;
  int lane = tid & 63, wid = tid >> 6;
  int l15 = lane & 15, lk = (lane >> 4) * 8;
  int wm = wid >> 2, wn4 = wid & 3;            // 2x4 waves, each 64x32 output

  // upper-triangle decode: pairs (brow<=bcol)
  int bi = blockIdx.x;
  int r = (int)((65.0f - sqrtf(4225.0f - 8.0f * (float)bi)) * 0.5f);
  if (r < 0) r = 0; if (r > 31) r = 31;
  while (r * (65 - r) / 2 > bi) --r;
  while ((r + 1) * (64 - r) / 2 <= bi) ++r;
  int brow = r;
  int bcol = r + (bi - r * (65 - r) / 2);
  bool diag = (brow == bcol);

  int srow = tid >> 3;
  int swzel = ((tid & 7) ^ (srow & 7)) * 8;
  const __hip_bfloat16* gA0 = wb + (size_t)(brow * 128 + srow) * DDIM + swzel;
  const __hip_bfloat16* gA1 = gA0 + (size_t)64 * DDIM;
  const __hip_bfloat16* gB0 = wb + (size_t)(bcol * 128 + srow) * DDIM + swzel;
  const __hip_bfloat16* gB1 = gB0 + (size_t)64 * DDIM;
  int ldst = tid * 16;

#define STAGE(bufbase, k0)                                                                  \
  do {                                                                                      \
    __builtin_amdgcn_global_load_lds((gvoid*)(gA0 + (k0)), (lvoid*)(smem + (bufbase) + ldst),         16, 0, 0); \
    __builtin_amdgcn_global_load_lds((gvoid*)(gA1 + (k0)), (lvoid*)(smem + (bufbase) + 8192 + ldst),  16, 0, 0); \
    __builtin_amdgcn_global_load_lds((gvoid*)(gB0 + (k0)), (lvoid*)(smem + (bufbase) + 16384 + ldst), 16, 0, 0); \
    __builtin_amdgcn_global_load_lds((gvoid*)(gB1 + (k0)), (lvoid*)(smem + (bufbase) + 24576 + ldst), 16, 0, 0); \
  } while (0)

  int xorb = (l15 & 7) << 4;
  int aoff = (wm * 64 + l15) * 128;
  int boff = 16384 + (wn4 * 32 + l15) * 128;

  frag_cd acc[4][2] = {};

  STAGE(0, 0);                                 // group 0 in flight (4 loads/wave)
  int cur = 0;
  for (int t = 0; t < 16; t++) {
    if (t < 15) {
      STAGE((cur ^ 1) * 32768, (t + 1) * 64);  // group t+1 in flight (4 more)
      asm volatile("s_waitcnt vmcnt(4)" ::: "memory");   // group t landed
    } else {
      asm volatile("s_waitcnt vmcnt(0)" ::: "memory");   // final group landed
    }
    __builtin_amdgcn_sched_barrier(0);
    __builtin_amdgcn_s_barrier();              // all waves' group-t data visible
    __builtin_amdgcn_sched_barrier(0);

    const char* base = smem + cur * 32768;
    const char* pa0 = base + aoff;
    const char* pb0 = base + boff;
    #pragma unroll
    for (int ks = 0; ks < 2; ks++) {
      int off = ((ks * 32 + lk) * 2) ^ xorb;
      frag_ab a[4], b[2];
      #pragma unroll
      for (int m = 0; m < 4; m++) a[m] = *(const frag_ab*)(const void*)(pa0 + m * 2048 + off);
      #pragma unroll
      for (int n = 0; n < 2; n++) b[n] = *(const frag_ab*)(const void*)(pb0 + n * 2048 + off);
      #pragma unroll
      for (int m = 0; m < 4; m++)
        #pragma unroll
        for (int n = 0; n < 2; n++)
          acc[m][n] = __builtin_amdgcn_mfma_f32_16x16x32_bf16(a[m], b[n], acc[m][n], 0, 0, 0);
    }

    __builtin_amdgcn_sched_barrier(0);
    __builtin_amdgcn_s_barrier();              // reads of buf[cur] done; next STAGE may overwrite
    __builtin_amdgcn_sched_barrier(0);
    cur ^= 1;
  }
#undef STAGE

  // exp in place
  #pragma unroll
  for (int m = 0; m < 4; m++)
    #pragma unroll
    for (int n = 0; n < 2; n++)
      #pragma unroll
      for (int j = 0; j < 4; j++)
        acc[m][n][j] = __expf(acc[m][n][j]);

  // C/D layout: col = lane&15, row = (lane>>4)*4 + reg
  int rg = (lane >> 4) * 4;
  int r0g = brow * 128 + wm * 64;
  int c0g = bcol * 128 + wn4 * 32 + l15;

  // normal tile (nibble-packed via lane pairing) + f32 row sums
  #pragma unroll
  for (int m = 0; m < 4; m++)
    #pragma unroll
    for (int j = 0; j < 4; j++) {
      int rglob = r0g + m * 16 + rg + j;
      float rsum = 0.f;
      #pragma unroll
      for (int n = 0; n < 2; n++) {
        float ex = acc[m][n][j];
        rsum += ex;
        int q = q4(ex);
        int qr = __shfl_xor(q, 1);             // partner column's nibble
        if (!(l15 & 1))
          e4[(size_t)rglob * 2048 + (unsigned)((c0g + n * 16) >> 1)] =
              (unsigned char)(q | (qr << 4));
      }
      rsum += __shfl_xor(rsum, 1);
      rsum += __shfl_xor(rsum, 2);
      rsum += __shfl_xor(rsum, 4);
      rsum += __shfl_xor(rsum, 8);
      if (l15 == 0) atomicAdd(&Sf[rglob], rsum);
    }

  if (!diag) {
    // mirror tile: rows of the mirror are our columns; j-pairs pack in-thread.
    #pragma unroll
    for (int n = 0; n < 2; n++) {
      int cg = c0g + n * 16;                   // global col = mirror row
      #pragma unroll
      for (int m = 0; m < 4; m++) {
        int b0 = q4(acc[m][n][0]) | (q4(acc[m][n][1]) << 4);
        int b1 = q4(acc[m][n][2]) | (q4(acc[m][n][3]) << 4);
        *(unsigned short*)(e4 + (size_t)cg * 2048 + ((unsigned)(r0g + m * 16 + rg) >> 1)) =
            (unsigned short)(b0 | (b1 << 8));
      }
      // col sums -> mirror rows' Sf
      float cs = 0.f;
      #pragma unroll
      for (int mm = 0; mm < 4; mm++)
        #pragma unroll
        for (int j = 0; j < 4; j++) cs += acc[mm][n][j];
      cs += __shfl_xor(cs, 16);
      cs += __shfl_xor(cs, 32);
      if (lane < 16) atomicAdd(&Sf[cg], cs);
    }
  }
}

// ---- Kernel C: per-sample loss (1 sample/block, no max, nt pred loads, u4 gather) ----
__global__ __launch_bounds__(256) void k_loss(const float* __restrict__ pred,
                                              const int* __restrict__ tgt,
                                              const unsigned char* __restrict__ e4,
                                              const float* __restrict__ Sf,
                                              float* __restrict__ part) {
  __shared__ float reds[4], redq[4], redp[4];
  int i = blockIdx.x, t = threadIdx.x;
  int tg = tgt[i];
  const f32x4* pr = (const f32x4*)(pred + (size_t)i * CDIM);
  const unsigned short* er = (const unsigned short*)(e4 + (size_t)tg * 2048);

  float se = 0.f, sp = 0.f, qd = 0.f;
  #pragma unroll
  for (int j = 0; j < 4; j++) {
    f32x4 v = __builtin_nontemporal_load(pr + t + j * 256);
    unsigned int u = er[t + j * 256];          // 4 nibbles = 4 columns
    se += (__expf(v[0]) + __expf(v[1])) + (__expf(v[2]) + __expf(v[3]));
    sp += (v[0] + v[1]) + (v[2] + v[3]);
    qd += (float)(u & 15u) * v[0] +
          (float)((u >> 4) & 15u) * v[1] +
          (float)((u >> 8) & 15u) * v[2] +
          (float)(u >> 12) * v[3];
  }
  #pragma unroll
  for (int off = 32; off; off >>= 1) {
    se += __shfl_xor(se, off);
    sp += __shfl_xor(sp, off);
    qd += __shfl_xor(qd, off);
  }
  if ((t & 63) == 0) { reds[t >> 6] = se; redq[t >> 6] = qd; redp[t >> 6] = sp; }
  __syncthreads();
  if (t == 0) {
    se = (reds[0] + reds[1]) + (reds[2] + reds[3]);
    qd = (redq[0] + redq[1]) + (redq[2] + redq[3]);
    sp = (redp[0] + redp[1]) + (redp[2] + redp[3]);
    float dot = QSCALE * qd + QBASE * sp;
    float lse = __logf(se);
    float pt = pred[(size_t)i * CDIM + tg];
    float ce = lse - pt;
    float S = Sf[tg];
    float t2 = (S * lse - dot - EDIAG * ce) / (S - EDIAG);
    part[i] = 0.9f * ce + 0.1f * t2;
  }
}

// ---- Kernel D: deterministic final reduce ----
__global__ __launch_bounds__(256) void k_final(const float* __restrict__ part,
                                               float* __restrict__ out) {
  __shared__ float red[4];
  int t = threadIdx.x;
  float s = 0.f;
  for (int i = t; i < BDIM; i += 256) s += part[i];
  s = block_sum(s, red);
  if (t == 0) out[0] = s * (1.0f / BDIM);
}

extern "C" void kernel_launch(void* const* d_in, const int* in_sizes, int n_in,
                              void* d_out, int out_size, void* d_ws, size_t ws_size,
                              hipStream_t stream) {
  const float* pred = (const float*)d_in[0];
  const float* weight = (const float*)d_in[1];
  const int* target = (const int*)d_in[2];
  float* out = (float*)d_out;
  char* ws = (char*)d_ws;

  __hip_bfloat16* wnb = (__hip_bfloat16*)ws;                          // 8 MB
  unsigned char* e4 = (unsigned char*)(ws + (size_t)(8u << 20));      // 8 MB (u4-packed)
  float* Sf   = (float*)(ws + (size_t)(16u << 20));                   // 16 KB
  float* part = (float*)(ws + (size_t)(16u << 20) + 16384);           // 64 KB

  k_norm<<<dim3(CDIM), dim3(256), 0, stream>>>(weight, wnb, Sf);
  k_simexp<<<dim3(528), dim3(512), 0, stream>>>(wnb, e4, Sf);
  k_loss<<<dim3(BDIM), dim3(256), 0, stream>>>(pred, target, e4, Sf, part);
  k_final<<<dim3(1), dim3(256), 0, stream>>>(part, out);
}

// Round 15
// 115.154 us; speedup vs baseline: 1.3560x; 1.0095x over previous
//
#include <hip/hip_runtime.h>
#include <hip/hip_bf16.h>

#define CDIM 4096
#define DDIM 1024
#define BDIM 16384
#define EDIAG 2.7182818284590452f
#define QBASE 0.36787944f          // e^-1
#define QSCALE 0.15669957f         // (e - e^-1)/15
#define QINV 6.3816357f            // 1/QSCALE

using frag_ab = __attribute__((ext_vector_type(8))) short;   // 8 bf16 (4 VGPRs)
using frag_cd = __attribute__((ext_vector_type(4))) float;   // 4 fp32
using f32x4   = __attribute__((ext_vector_type(4))) float;   // native vec for nt-load

typedef __attribute__((address_space(1))) const void gvoid;
typedef __attribute__((address_space(3))) void lvoid;

__device__ __forceinline__ float block_sum(float v, float* red) {
  int t = threadIdx.x;
  #pragma unroll
  for (int off = 32; off; off >>= 1) v += __shfl_xor(v, off);
  __syncthreads();
  if ((t & 63) == 0) red[t >> 6] = v;
  __syncthreads();
  return (red[0] + red[1]) + (red[2] + red[3]);
}

__device__ __forceinline__ unsigned short f2bfbits(float f) {
  __hip_bfloat16 b = __float2bfloat16(f);
  return *(unsigned short*)&b;
}

// 4-bit linear quant of e-values (e in [e^-1, e])
__device__ __forceinline__ int q4(float ex) {
  int q = __float2int_rn((ex - QBASE) * QINV);
  return min(15, max(0, q));
}

// ---- Kernel A: wn = bf16( weight_row / max(||row||, 1e-8) ); zero Sf ----
__global__ __launch_bounds__(256) void k_norm(const float* __restrict__ w,
                                              __hip_bfloat16* __restrict__ wnb,
                                              float* __restrict__ Sf) {
  __shared__ float red[4];
  __shared__ float s_inv;
  int row = blockIdx.x, t = threadIdx.x;
  const float4* wr = (const float4*)(w + (size_t)row * DDIM);
  float4 x = wr[t];
  float ss = (x.x * x.x + x.y * x.y) + (x.z * x.z + x.w * x.w);
  ss = block_sum(ss, red);
  if (t == 0) {
    s_inv = 1.0f / fmaxf(sqrtf(ss), 1e-8f);
    Sf[row] = 0.0f;
  }
  __syncthreads();
  float inv = s_inv;
  ushort4 o;
  o.x = f2bfbits(x.x * inv);
  o.y = f2bfbits(x.y * inv);
  o.z = f2bfbits(x.z * inv);
  o.w = f2bfbits(x.w * inv);
  *(ushort4*)(wnb + (size_t)row * DDIM + t * 4) = o;
}

// ---- Kernel B: e4 = u4(exp(wn @ wn^T)), upper-triangle blocks only ----
// 128x128 tile, BK=64, 8 waves (2Mx4N), double-buffered swizzled LDS,
// T4 counted-vmcnt K-loop (R14 config, frozen).
__global__ __launch_bounds__(512) void k_simexp(const __hip_bfloat16* __restrict__ wb,
                                                unsigned char* __restrict__ e4,
                                                float* __restrict__ Sf) {
  __shared__ char smem[65536];                 // 2 bufs x (A[128][64]|B[128][64]) bf16
  int tid = threadIdx.x;
  int lane = tid & 63, wid = tid >> 6;
  int l15 = lane & 15, lk = (lane >> 4) * 8;
  int wm = wid >> 2, wn4 = wid & 3;            // 2x4 waves, each 64x32 output

  // upper-triangle decode: pairs (brow<=bcol)
  int bi = blockIdx.x;
  int r = (int)((65.0f - sqrtf(4225.0f - 8.0f * (float)bi)) * 0.5f);
  if (r < 0) r = 0; if (r > 31) r = 31;
  while (r * (65 - r) / 2 > bi) --r;
  while ((r + 1) * (64 - r) / 2 <= bi) ++r;
  int brow = r;
  int bcol = r + (bi - r * (65 - r) / 2);
  bool diag = (brow == bcol);

  int srow = tid >> 3;
  int swzel = ((tid & 7) ^ (srow & 7)) * 8;
  const __hip_bfloat16* gA0 = wb + (size_t)(brow * 128 + srow) * DDIM + swzel;
  const __hip_bfloat16* gA1 = gA0 + (size_t)64 * DDIM;
  const __hip_bfloat16* gB0 = wb + (size_t)(bcol * 128 + srow) * DDIM + swzel;
  const __hip_bfloat16* gB1 = gB0 + (size_t)64 * DDIM;
  int ldst = tid * 16;

#define STAGE(bufbase, k0)                                                                  \
  do {                                                                                      \
    __builtin_amdgcn_global_load_lds((gvoid*)(gA0 + (k0)), (lvoid*)(smem + (bufbase) + ldst),         16, 0, 0); \
    __builtin_amdgcn_global_load_lds((gvoid*)(gA1 + (k0)), (lvoid*)(smem + (bufbase) + 8192 + ldst),  16, 0, 0); \
    __builtin_amdgcn_global_load_lds((gvoid*)(gB0 + (k0)), (lvoid*)(smem + (bufbase) + 16384 + ldst), 16, 0, 0); \
    __builtin_amdgcn_global_load_lds((gvoid*)(gB1 + (k0)), (lvoid*)(smem + (bufbase) + 24576 + ldst), 16, 0, 0); \
  } while (0)

  int xorb = (l15 & 7) << 4;
  int aoff = (wm * 64 + l15) * 128;
  int boff = 16384 + (wn4 * 32 + l15) * 128;

  frag_cd acc[4][2] = {};

  STAGE(0, 0);                                 // group 0 in flight (4 loads/wave)
  int cur = 0;
  for (int t = 0; t < 16; t++) {
    if (t < 15) {
      STAGE((cur ^ 1) * 32768, (t + 1) * 64);  // group t+1 in flight (4 more)
      asm volatile("s_waitcnt vmcnt(4)" ::: "memory");   // group t landed
    } else {
      asm volatile("s_waitcnt vmcnt(0)" ::: "memory");   // final group landed
    }
    __builtin_amdgcn_sched_barrier(0);
    __builtin_amdgcn_s_barrier();              // all waves' group-t data visible
    __builtin_amdgcn_sched_barrier(0);

    const char* base = smem + cur * 32768;
    const char* pa0 = base + aoff;
    const char* pb0 = base + boff;
    #pragma unroll
    for (int ks = 0; ks < 2; ks++) {
      int off = ((ks * 32 + lk) * 2) ^ xorb;
      frag_ab a[4], b[2];
      #pragma unroll
      for (int m = 0; m < 4; m++) a[m] = *(const frag_ab*)(const void*)(pa0 + m * 2048 + off);
      #pragma unroll
      for (int n = 0; n < 2; n++) b[n] = *(const frag_ab*)(const void*)(pb0 + n * 2048 + off);
      #pragma unroll
      for (int m = 0; m < 4; m++)
        #pragma unroll
        for (int n = 0; n < 2; n++)
          acc[m][n] = __builtin_amdgcn_mfma_f32_16x16x32_bf16(a[m], b[n], acc[m][n], 0, 0, 0);
    }

    __builtin_amdgcn_sched_barrier(0);
    __builtin_amdgcn_s_barrier();              // reads of buf[cur] done; next STAGE may overwrite
    __builtin_amdgcn_sched_barrier(0);
    cur ^= 1;
  }
#undef STAGE

  // exp in place
  #pragma unroll
  for (int m = 0; m < 4; m++)
    #pragma unroll
    for (int n = 0; n < 2; n++)
      #pragma unroll
      for (int j = 0; j < 4; j++)
        acc[m][n][j] = __expf(acc[m][n][j]);

  // C/D layout: col = lane&15, row = (lane>>4)*4 + reg
  int rg = (lane >> 4) * 4;
  int r0g = brow * 128 + wm * 64;
  int c0g = bcol * 128 + wn4 * 32 + l15;

  // normal tile (nibble-packed via lane pairing) + f32 row sums
  #pragma unroll
  for (int m = 0; m < 4; m++)
    #pragma unroll
    for (int j = 0; j < 4; j++) {
      int rglob = r0g + m * 16 + rg + j;
      float rsum = 0.f;
      #pragma unroll
      for (int n = 0; n < 2; n++) {
        float ex = acc[m][n][j];
        rsum += ex;
        int q = q4(ex);
        int qr = __shfl_xor(q, 1);             // partner column's nibble
        if (!(l15 & 1))
          e4[(size_t)rglob * 2048 + (unsigned)((c0g + n * 16) >> 1)] =
              (unsigned char)(q | (qr << 4));
      }
      rsum += __shfl_xor(rsum, 1);
      rsum += __shfl_xor(rsum, 2);
      rsum += __shfl_xor(rsum, 4);
      rsum += __shfl_xor(rsum, 8);
      if (l15 == 0) atomicAdd(&Sf[rglob], rsum);
    }

  if (!diag) {
    // mirror tile: rows of the mirror are our columns; j-pairs pack in-thread.
    #pragma unroll
    for (int n = 0; n < 2; n++) {
      int cg = c0g + n * 16;                   // global col = mirror row
      #pragma unroll
      for (int m = 0; m < 4; m++) {
        int b0 = q4(acc[m][n][0]) | (q4(acc[m][n][1]) << 4);
        int b1 = q4(acc[m][n][2]) | (q4(acc[m][n][3]) << 4);
        *(unsigned short*)(e4 + (size_t)cg * 2048 + ((unsigned)(r0g + m * 16 + rg) >> 1)) =
            (unsigned short)(b0 | (b1 << 8));
      }
      // col sums -> mirror rows' Sf
      float cs = 0.f;
      #pragma unroll
      for (int mm = 0; mm < 4; mm++)
        #pragma unroll
        for (int j = 0; j < 4; j++) cs += acc[mm][n][j];
      cs += __shfl_xor(cs, 16);
      cs += __shfl_xor(cs, 32);
      if (lane < 16) atomicAdd(&Sf[cg], cs);
    }
  }
}

// ---- Kernel C: per-sample loss. e4 row hoisted to LDS in ONE coalesced burst
// (2048 B = uint2/thread) so the pred stream carries only 4 VMEM loads/thread
// in flight (MSHR/queue relief); nibble decode reads LDS (same-word pairs = free).
__global__ __launch_bounds__(256) void k_loss(const float* __restrict__ pred,
                                              const int* __restrict__ tgt,
                                              const unsigned char* __restrict__ e4,
                                              const float* __restrict__ Sf,
                                              float* __restrict__ part) {
  __shared__ uint2 erow[256];                  // 2048 B = one e4 row
  __shared__ float reds[4], redq[4], redp[4];
  int i = blockIdx.x, t = threadIdx.x;
  int tg = tgt[i];
  erow[t] = ((const uint2*)(e4 + (size_t)tg * 2048))[t];
  const f32x4* pr = (const f32x4*)(pred + (size_t)i * CDIM);
  __syncthreads();
  const unsigned short* er = (const unsigned short*)erow;

  float se = 0.f, sp = 0.f, qd = 0.f;
  #pragma unroll
  for (int j = 0; j < 4; j++) {
    f32x4 v = __builtin_nontemporal_load(pr + t + j * 256);
    unsigned int u = er[t + j * 256];          // 4 nibbles = 4 columns (LDS)
    se += (__expf(v[0]) + __expf(v[1])) + (__expf(v[2]) + __expf(v[3]));
    sp += (v[0] + v[1]) + (v[2] + v[3]);
    qd += (float)(u & 15u) * v[0] +
          (float)((u >> 4) & 15u) * v[1] +
          (float)((u >> 8) & 15u) * v[2] +
          (float)(u >> 12) * v[3];
  }
  #pragma unroll
  for (int off = 32; off; off >>= 1) {
    se += __shfl_xor(se, off);
    sp += __shfl_xor(sp, off);
    qd += __shfl_xor(qd, off);
  }
  if ((t & 63) == 0) { reds[t >> 6] = se; redq[t >> 6] = qd; redp[t >> 6] = sp; }
  __syncthreads();
  if (t == 0) {
    se = (reds[0] + reds[1]) + (reds[2] + reds[3]);
    qd = (redq[0] + redq[1]) + (redq[2] + redq[3]);
    sp = (redp[0] + redp[1]) + (redp[2] + redp[3]);
    float dot = QSCALE * qd + QBASE * sp;
    float lse = __logf(se);
    float pt = pred[(size_t)i * CDIM + tg];
    float ce = lse - pt;
    float S = Sf[tg];
    float t2 = (S * lse - dot - EDIAG * ce) / (S - EDIAG);
    part[i] = 0.9f * ce + 0.1f * t2;
  }
}

// ---- Kernel D: deterministic final reduce ----
__global__ __launch_bounds__(256) void k_final(const float* __restrict__ part,
                                               float* __restrict__ out) {
  __shared__ float red[4];
  int t = threadIdx.x;
  float s = 0.f;
  for (int i = t; i < BDIM; i += 256) s += part[i];
  s = block_sum(s, red);
  if (t == 0) out[0] = s * (1.0f / BDIM);
}

extern "C" void kernel_launch(void* const* d_in, const int* in_sizes, int n_in,
                              void* d_out, int out_size, void* d_ws, size_t ws_size,
                              hipStream_t stream) {
  const float* pred = (const float*)d_in[0];
  const float* weight = (const float*)d_in[1];
  const int* target = (const int*)d_in[2];
  float* out = (float*)d_out;
  char* ws = (char*)d_ws;

  __hip_bfloat16* wnb = (__hip_bfloat16*)ws;                          // 8 MB
  unsigned char* e4 = (unsigned char*)(ws + (size_t)(8u << 20));      // 8 MB (u4-packed)
  float* Sf   = (float*)(ws + (size_t)(16u << 20));                   // 16 KB
  float* part = (float*)(ws + (size_t)(16u << 20) + 16384);           // 64 KB

  k_norm<<<dim3(CDIM), dim3(256), 0, stream>>>(weight, wnb, Sf);
  k_simexp<<<dim3(528), dim3(512), 0, stream>>>(wnb, e4, Sf);
  k_loss<<<dim3(BDIM), dim3(256), 0, stream>>>(pred, target, e4, Sf, part);
  k_final<<<dim3(1), dim3(256), 0, stream>>>(part, out);
}